// Round 1
// baseline (231.389 us; speedup 1.0000x reference)
//
#include <hip/hip_runtime.h>
#include <hip/hip_bf16.h>
#include <stdint.h>

#define B_ 8
#define C_ 512
#define T_ 4096
#define O_ 512
#define KK_ 1536   /* C*3 */
#define EPS_ 1e-8f

#define TILE 128
#define LDP 40     /* padded LDS row length in ushorts (32 + 8 pad, 16B aligned rows) */

typedef unsigned short ushort_t;
typedef __attribute__((ext_vector_type(4))) float f32x4;
typedef __attribute__((ext_vector_type(8))) short bf16x8;

__device__ __forceinline__ ushort_t f2bf(float f) {
  union { float f; uint32_t u; } x; x.f = f;
  uint32_t u = x.u;
  uint32_t r = (u + 0x7FFFu + ((u >> 16) & 1u)) >> 16;
  return (ushort_t)r;
}

// ---------------- sim reduction: nn[t] = sum_c e^2, dl[t] = sum_c e[t]*e[t-1] ---------
// grid: (T/256, B), block: (64,4). tx owns 4 consecutive t; ty owns a 128-wide c-chunk.
__global__ void sim_reduce_kernel(const float* __restrict__ emb,
                                  float* __restrict__ nn_out,
                                  float* __restrict__ dl_out) {
  const int b = blockIdx.y;
  const int t0 = (blockIdx.x * 64 + threadIdx.x) * 4;
  const int cty = threadIdx.y;
  float nn0=0.f,nn1=0.f,nn2=0.f,nn3=0.f;
  float dl0=0.f,dl1=0.f,dl2=0.f,dl3=0.f;
  const float* base = emb + (size_t)b * C_ * T_;
  for (int c = cty * 128; c < cty * 128 + 128; ++c) {
    const float* row = base + (size_t)c * T_;
    float4 v = *(const float4*)(row + t0);
    float el = (t0 > 0) ? row[t0 - 1] : 0.f;
    nn0 += v.x*v.x; nn1 += v.y*v.y; nn2 += v.z*v.z; nn3 += v.w*v.w;
    dl0 += v.x*el;  dl1 += v.y*v.x; dl2 += v.z*v.y; dl3 += v.w*v.z;
  }
  __shared__ float red[4][64*8];
  float* myr = &red[cty][threadIdx.x * 8];
  if (cty != 0) {
    myr[0]=nn0; myr[1]=nn1; myr[2]=nn2; myr[3]=nn3;
    myr[4]=dl0; myr[5]=dl1; myr[6]=dl2; myr[7]=dl3;
  }
  __syncthreads();
  if (cty == 0) {
    for (int q = 1; q < 4; ++q) {
      float* r = &red[q][threadIdx.x * 8];
      nn0+=r[0]; nn1+=r[1]; nn2+=r[2]; nn3+=r[3];
      dl0+=r[4]; dl1+=r[5]; dl2+=r[6]; dl3+=r[7];
    }
    float* nb = nn_out + (size_t)b * T_ + t0;
    float* db = dl_out + (size_t)b * T_ + t0;
    nb[0]=nn0; nb[1]=nn1; nb[2]=nn2; nb[3]=nn3;
    db[0]=dl0; db[1]=dl1; db[2]=dl2; db[3]=dl3;
  }
}

// ---------------- sim finalize: sim[b][0]=sim_l, [1]=sim_c, [2]=sim_r ----------------
__global__ void sim_finalize_kernel(const float* __restrict__ nn,
                                    const float* __restrict__ dl,
                                    float* __restrict__ sim) {
  const int idx = blockIdx.x * 256 + threadIdx.x;
  if (idx >= B_ * T_) return;
  const int b = idx >> 12;
  const int t = idx & (T_ - 1);
  const float* nnb = nn + (size_t)b * T_;
  const float* dlb = dl + (size_t)b * T_;
  float nncur = nnb[t];
  float ncur = fmaxf(sqrtf(nncur), EPS_);
  float sc = nncur / (ncur * ncur);
  float sl = 0.f, sr = 0.f;
  if (t > 0) {
    float np = fmaxf(sqrtf(nnb[t - 1]), EPS_);
    sl = dlb[t] / (ncur * np);
  }
  if (t < T_ - 1) {
    float nx = fmaxf(sqrtf(nnb[t + 1]), EPS_);
    sr = dlb[t + 1] / (ncur * nx);
  }
  float* simb = sim + (size_t)b * 3 * T_;
  simb[t] = sl;
  simb[T_ + t] = sc;
  simb[2 * T_ + t] = sr;
}

// ---------------- weight f32 -> bf16 (layout [O][C*3] == flat) -----------------------
__global__ void wconv_kernel(const float* __restrict__ w, ushort_t* __restrict__ wbf) {
  const int idx = blockIdx.x * 256 + threadIdx.x;
  if (idx < O_ * KK_) wbf[idx] = f2bf(w[idx]);
}

// ---------------- main GEMM: out[b,o,t] = sum_j sim_j(t) * G_j[o,t] ------------------
// 128x128 tile, 4 waves (2x2), each wave 64x64 as 4x4 frags of 16x16x32 bf16 MFMA.
// K = 1536 split as 3 chunks of 512 (16 K-steps of 32); per-chunk per-column sim scale.
__global__ __launch_bounds__(256, 2)
void conv_gemm_kernel(const float* __restrict__ feat,
                      const ushort_t* __restrict__ wbf,
                      const float* __restrict__ sim,
                      float* __restrict__ out) {
  const int b = blockIdx.z;
  const int oBase = blockIdx.y * TILE;
  const int tBase = blockIdx.x * TILE;

  __shared__ __align__(16) ushort_t Al[TILE * LDP];  // [o-row][k] row-major, padded
  __shared__ __align__(16) ushort_t Bl[TILE * LDP];  // [t-col][k] row-major, padded

  const int tid = threadIdx.x;
  const int lane = tid & 63;
  const int wid = tid >> 6;
  const int wm = wid >> 1, wn = wid & 1;
  const int llo = lane & 15, lhi = lane >> 4;

  f32x4 cacc[4][4];
  f32x4 oacc[4][4];
  const f32x4 vzero = {0.f, 0.f, 0.f, 0.f};
  for (int m = 0; m < 4; ++m)
    for (int n = 0; n < 4; ++n) { cacc[m][n] = vzero; oacc[m][n] = vzero; }

  // A staging: 128 rows x 32 cols; thread -> (row = tid>>1, half = tid&1), 16 bf16 each
  const int arow = tid >> 1;
  const int ahalf = tid & 1;
  const ushort_t* aSrc = wbf + (size_t)(oBase + arow) * KK_ + ahalf * 16;
  ushort_t* aDst = &Al[arow * LDP + ahalf * 16];

  // B staging: 32 rows (i) x 128 cols (t); thread -> (irow = tid>>3, 16 t's)
  const int irow = tid >> 3;
  const int tloc0 = (tid & 7) * 16;
  const float* featB = feat + (size_t)b * C_ * T_;
  const float* simB = sim + (size_t)b * 3 * T_;

  for (int chunk = 0; chunk < 3; ++chunk) {
    for (int ks = 0; ks < 16; ++ks) {
      const int i0 = chunk * 512 + ks * 32;
      __syncthreads();  // previous step's frag reads done before we overwrite LDS
      // ---- stage A (weight tile, already bf16) ----
      {
        const ushort_t* s = aSrc + i0;
        uint4 v0 = *(const uint4*)(s);
        uint4 v1 = *(const uint4*)(s + 8);
        *(uint4*)(aDst) = v0;
        *(uint4*)(aDst + 8) = v1;
      }
      // ---- stage B (feature, shifted by k-1, f32 -> bf16, transposed write) ----
      {
        const int ig = i0 + irow;
        const int c = ig / 3;
        const int k = ig - c * 3;
        const int g0 = tBase + tloc0 + k - 1;
        const float* src = featB + (size_t)c * T_ + g0;
        ushort_t tmp[16];
        if (g0 >= 0 && g0 + 16 <= T_) {
          for (int q = 0; q < 4; ++q) {
            float4 v = *(const float4*)(src + q * 4);
            tmp[q*4+0] = f2bf(v.x); tmp[q*4+1] = f2bf(v.y);
            tmp[q*4+2] = f2bf(v.z); tmp[q*4+3] = f2bf(v.w);
          }
        } else {
          for (int q = 0; q < 16; ++q) {
            int g = g0 + q;
            float v = (g >= 0 && g < T_) ? src[q] : 0.f;
            tmp[q] = f2bf(v);
          }
        }
        ushort_t* bd = &Bl[irow];
        for (int q = 0; q < 16; ++q) bd[(tloc0 + q) * LDP] = tmp[q];
      }
      __syncthreads();
      // ---- compute: 16 MFMAs per wave ----
      bf16x8 af[4], bfr[4];
      for (int m = 0; m < 4; ++m)
        af[m] = *(const bf16x8*)&Al[(wm * 64 + m * 16 + llo) * LDP + lhi * 8];
      for (int n = 0; n < 4; ++n)
        bfr[n] = *(const bf16x8*)&Bl[(wn * 64 + n * 16 + llo) * LDP + lhi * 8];
      for (int m = 0; m < 4; ++m)
        for (int n = 0; n < 4; ++n)
          cacc[m][n] = __builtin_amdgcn_mfma_f32_16x16x32_bf16(af[m], bfr[n], cacc[m][n], 0, 0, 0);
    }
    // ---- chunk boundary: scale partial G_j by per-column sim_j, accumulate ----
    for (int n = 0; n < 4; ++n) {
      float s = simB[chunk * T_ + tBase + wn * 64 + n * 16 + llo];
      for (int m = 0; m < 4; ++m) {
        oacc[m][n] += s * cacc[m][n];
        cacc[m][n] = vzero;
      }
    }
  }

  // ---- epilogue: D layout col=lane&15, row=(lane>>4)*4+reg ----
  float* outB = out + ((size_t)b * O_ + oBase) * T_ + tBase;
  for (int m = 0; m < 4; ++m) {
    const int r0 = wm * 64 + m * 16 + lhi * 4;
    for (int n = 0; n < 4; ++n) {
      const int cg = wn * 64 + n * 16 + llo;
      for (int r = 0; r < 4; ++r)
        outB[(size_t)(r0 + r) * T_ + cg] = oacc[m][n][r];
    }
  }
}

extern "C" void kernel_launch(void* const* d_in, const int* in_sizes, int n_in,
                              void* d_out, int out_size, void* d_ws, size_t ws_size,
                              hipStream_t stream) {
  const float* feature   = (const float*)d_in[0];
  const float* embedding = (const float*)d_in[1];
  const float* weight    = (const float*)d_in[2];
  float* out = (float*)d_out;

  float* ws  = (float*)d_ws;
  float* nn  = ws;                     // B*T
  float* dl  = ws + (size_t)B_ * T_;   // B*T
  float* sim = ws + (size_t)2 * B_ * T_;           // B*3*T
  ushort_t* wbf = (ushort_t*)(ws + (size_t)5 * B_ * T_);  // O*KK bf16

  sim_reduce_kernel<<<dim3(T_ / 256, B_), dim3(64, 4), 0, stream>>>(embedding, nn, dl);
  sim_finalize_kernel<<<dim3((B_ * T_) / 256), 256, 0, stream>>>(nn, dl, sim);
  wconv_kernel<<<dim3((O_ * KK_) / 256), 256, 0, stream>>>(weight, wbf);
  conv_gemm_kernel<<<dim3(T_ / TILE, O_ / TILE, B_), 256, 0, stream>>>(feature, wbf, sim, out);
}

// Round 2
// 136.988 us; speedup vs baseline: 1.6891x; 1.6891x over previous
//
#include <hip/hip_runtime.h>
#include <hip/hip_bf16.h>
#include <stdint.h>

#define B_ 8
#define C_ 512
#define T_ 4096
#define O_ 512
#define KP_ 1728   /* padded K: 3 groups x 3 k x 192 */
#define EPS_ 1e-8f

#define TILE 128
#define BK 64
#define FTP_ROWS 4104  /* rows 0..4098 used (t=-1..T, +1 overrun pad), stride padded to 4104 */

typedef unsigned short ushort_t;
typedef __attribute__((ext_vector_type(4))) float f32x4;
typedef __attribute__((ext_vector_type(8))) short bf16x8;

__device__ __forceinline__ ushort_t f2bf(float f) {
  union { float f; uint32_t u; } x; x.f = f;
  uint32_t u = x.u;
  uint32_t r = (u + 0x7FFFu + ((u >> 16) & 1u)) >> 16;
  return (ushort_t)r;
}

#define GLOAD16(gsrc, ldst) \
  __builtin_amdgcn_global_load_lds((const __attribute__((address_space(1))) unsigned int*)(gsrc), \
                                   (__attribute__((address_space(3))) unsigned int*)(ldst), 16, 0, 0)

// ---------------- sim reduction: nn[t] = sum_c e^2, dl[t] = sum_c e[t]*e[t-1] ---------
__global__ void sim_reduce_kernel(const float* __restrict__ emb,
                                  float* __restrict__ nn_out,
                                  float* __restrict__ dl_out) {
  const int b = blockIdx.y;
  const int t0 = (blockIdx.x * 64 + threadIdx.x) * 4;
  const int cty = threadIdx.y;
  float nn0=0.f,nn1=0.f,nn2=0.f,nn3=0.f;
  float dl0=0.f,dl1=0.f,dl2=0.f,dl3=0.f;
  const float* base = emb + (size_t)b * C_ * T_;
  for (int c = cty * 128; c < cty * 128 + 128; ++c) {
    const float* row = base + (size_t)c * T_;
    float4 v = *(const float4*)(row + t0);
    float el = (t0 > 0) ? row[t0 - 1] : 0.f;
    nn0 += v.x*v.x; nn1 += v.y*v.y; nn2 += v.z*v.z; nn3 += v.w*v.w;
    dl0 += v.x*el;  dl1 += v.y*v.x; dl2 += v.z*v.y; dl3 += v.w*v.z;
  }
  __shared__ float red[4][64*8];
  float* myr = &red[cty][threadIdx.x * 8];
  if (cty != 0) {
    myr[0]=nn0; myr[1]=nn1; myr[2]=nn2; myr[3]=nn3;
    myr[4]=dl0; myr[5]=dl1; myr[6]=dl2; myr[7]=dl3;
  }
  __syncthreads();
  if (cty == 0) {
    for (int q = 1; q < 4; ++q) {
      float* r = &red[q][threadIdx.x * 8];
      nn0+=r[0]; nn1+=r[1]; nn2+=r[2]; nn3+=r[3];
      dl0+=r[4]; dl1+=r[5]; dl2+=r[6]; dl3+=r[7];
    }
    float* nb = nn_out + (size_t)b * T_ + t0;
    float* db = dl_out + (size_t)b * T_ + t0;
    nb[0]=nn0; nb[1]=nn1; nb[2]=nn2; nb[3]=nn3;
    db[0]=dl0; db[1]=dl1; db[2]=dl2; db[3]=dl3;
  }
}

// ---------------- sim finalize ----------------
__global__ void sim_finalize_kernel(const float* __restrict__ nn,
                                    const float* __restrict__ dl,
                                    float* __restrict__ sim) {
  const int idx = blockIdx.x * 256 + threadIdx.x;
  if (idx >= B_ * T_) return;
  const int b = idx >> 12;
  const int t = idx & (T_ - 1);
  const float* nnb = nn + (size_t)b * T_;
  const float* dlb = dl + (size_t)b * T_;
  float nncur = nnb[t];
  float ncur = fmaxf(sqrtf(nncur), EPS_);
  float sc = nncur / (ncur * ncur);
  float sl = 0.f, sr = 0.f;
  if (t > 0) {
    float np = fmaxf(sqrtf(nnb[t - 1]), EPS_);
    sl = dlb[t] / (ncur * np);
  }
  if (t < T_ - 1) {
    float nx = fmaxf(sqrtf(nnb[t + 1]), EPS_);
    sr = dlb[t + 1] / (ncur * nx);
  }
  float* simb = sim + (size_t)b * 3 * T_;
  simb[t] = sl;
  simb[T_ + t] = sc;
  simb[2 * T_ + t] = sr;
}

// ---------------- weight permute+pad: wbf[o][p], p=(g*3+k)*192+j, c=(c_lo&~7)+j ------
__global__ void wperm_kernel(const float* __restrict__ w, ushort_t* __restrict__ wbf) {
  const int idx = blockIdx.x * 256 + threadIdx.x;
  if (idx >= O_ * KP_) return;
  const int o = idx / KP_;
  const int p = idx - o * KP_;
  const int g = p / 576; const int r = p - g * 576;
  const int k = r / 192; const int j = r - k * 192;
  const int c_lo = (512 * g - k + 2) / 3;
  const int c_hi = (512 * g + 511 - k) / 3;
  const int c = (c_lo & ~7) + j;
  float v = (c >= c_lo && c <= c_hi) ? w[((size_t)o * C_ + c) * 3 + k] : 0.f;
  wbf[idx] = f2bf(v);
}

// ---------------- zero pad rows of Ftp (t=-1, t=T, overrun row) ----------------------
__global__ void zero_pads_kernel(ushort_t* __restrict__ Ftp) {
  const int b = blockIdx.x;
  const int rsel = blockIdx.y;
  const int row = (rsel == 0) ? 0 : (rsel == 1 ? T_ + 1 : T_ + 2);
  uint4* dst = (uint4*)(Ftp + ((size_t)b * FTP_ROWS + row) * 512);
  if (threadIdx.x < 64) dst[threadIdx.x] = make_uint4(0, 0, 0, 0);
}

// ---------------- feature transpose+convert: Ftp[b][t+1][c] = bf16(feat[b][c][t]) ----
__global__ void transpose_kernel(const float* __restrict__ feat, ushort_t* __restrict__ Ftp) {
  const int b = blockIdx.z;
  const int c0 = blockIdx.y * 64;
  const int t0 = blockIdx.x * 64;
  __shared__ ushort_t LT[64 * 72];
  const int tid = threadIdx.x;
  {
    const int cl = tid >> 2;
    const int tq = (tid & 3) * 16;
    const float* src = feat + ((size_t)b * C_ + c0 + cl) * T_ + t0 + tq;
    for (int q = 0; q < 4; ++q) {
      float4 v = *(const float4*)(src + q * 4);
      const int t = tq + q * 4;
      LT[(t + 0) * 72 + cl] = f2bf(v.x);
      LT[(t + 1) * 72 + cl] = f2bf(v.y);
      LT[(t + 2) * 72 + cl] = f2bf(v.z);
      LT[(t + 3) * 72 + cl] = f2bf(v.w);
    }
  }
  __syncthreads();
  {
    const int tl = tid >> 2;
    const int cq = (tid & 3) * 16;
    ushort_t* dst = Ftp + ((size_t)b * FTP_ROWS + t0 + tl + 1) * 512 + c0 + cq;
    *(uint4*)(dst) = *(const uint4*)&LT[tl * 72 + cq];
    *(uint4*)(dst + 8) = *(const uint4*)&LT[tl * 72 + cq + 8];
  }
}

// ---------------- main GEMM: 128x128 tile, BK=64, global_load_lds, 2-barrier ---------
__global__ __launch_bounds__(256, 2)
void conv_gemm_kernel(const ushort_t* __restrict__ Ftp,
                      const ushort_t* __restrict__ wbf,
                      const float* __restrict__ sim,
                      float* __restrict__ out) {
  const int b = blockIdx.z;
  const int oBase = blockIdx.y * TILE;
  const int tBase = blockIdx.x * TILE;

  __shared__ __align__(16) ushort_t Al[TILE * BK];
  __shared__ __align__(16) ushort_t Bl[TILE * BK];

  const int tid = threadIdx.x;
  const int lane = tid & 63;
  const int wid = tid >> 6;
  const int wm = wid >> 1, wn = wid & 1;
  const int llo = lane & 15, lhi = lane >> 4;

  // staging geometry: wave w, instr i covers rows w*32+i*8 .. +8; lane -> (row, 16B chunk)
  const int srow = wid * 32 + (lane >> 3);
  const int scol = (lane & 7) * 8;

  const ushort_t* aSrc = wbf + (size_t)(oBase + srow) * KP_ + scol;
  const ushort_t* ftpB = Ftp + (size_t)b * FTP_ROWS * 512;
  const float* simB = sim + (size_t)b * 3 * T_;

  f32x4 cacc[4][4], oacc[4][4];
  const f32x4 vzero = {0.f, 0.f, 0.f, 0.f};
  for (int m = 0; m < 4; ++m)
    for (int n = 0; n < 4; ++n) { cacc[m][n] = vzero; oacc[m][n] = vzero; }

  for (int g = 0; g < 3; ++g) {
    for (int k = 0; k < 3; ++k) {
      const int c_lo = (512 * g - k + 2) / 3;
      const int c_st = c_lo & ~7;
      const ushort_t* bSrc = ftpB + (size_t)(tBase + srow + k) * 512 + c_st + scol;
      const int pbase = (g * 3 + k) * 192;
#pragma unroll
      for (int jb = 0; jb < 3; ++jb) {
        __syncthreads();   // previous compute's LDS reads done
#pragma unroll
        for (int i = 0; i < 4; ++i) {
          GLOAD16(aSrc + (size_t)(i * 8) * KP_ + pbase + jb * 64, &Al[(wid * 32 + i * 8) * BK]);
          GLOAD16(bSrc + (size_t)(i * 8) * 512 + jb * 64,         &Bl[(wid * 32 + i * 8) * BK]);
        }
        __syncthreads();   // implies vmcnt(0) drain: tiles ready
#pragma unroll
        for (int h = 0; h < 2; ++h) {
          bf16x8 af[4], bfr[4];
#pragma unroll
          for (int m = 0; m < 4; ++m)
            af[m] = *(const bf16x8*)&Al[(wm * 64 + m * 16 + llo) * BK + h * 32 + lhi * 8];
#pragma unroll
          for (int n = 0; n < 4; ++n)
            bfr[n] = *(const bf16x8*)&Bl[(wn * 64 + n * 16 + llo) * BK + h * 32 + lhi * 8];
#pragma unroll
          for (int m = 0; m < 4; ++m)
#pragma unroll
            for (int n = 0; n < 4; ++n)
              cacc[m][n] = __builtin_amdgcn_mfma_f32_16x16x32_bf16(af[m], bfr[n], cacc[m][n], 0, 0, 0);
        }
      }
    }
    // group boundary: scale partial sums by sim_g(t)
#pragma unroll
    for (int n = 0; n < 4; ++n) {
      float s = simB[g * T_ + tBase + wn * 64 + n * 16 + llo];
#pragma unroll
      for (int m = 0; m < 4; ++m) {
        oacc[m][n] += s * cacc[m][n];
        cacc[m][n] = vzero;
      }
    }
  }

  // epilogue: D layout col=lane&15, row=(lane>>4)*4+reg
  float* outB = out + ((size_t)b * O_ + oBase) * T_ + tBase;
#pragma unroll
  for (int m = 0; m < 4; ++m) {
    const int r0 = wm * 64 + m * 16 + lhi * 4;
#pragma unroll
    for (int n = 0; n < 4; ++n) {
      const int cg = wn * 64 + n * 16 + llo;
#pragma unroll
      for (int r = 0; r < 4; ++r)
        outB[(size_t)(r0 + r) * T_ + cg] = oacc[m][n][r];
    }
  }
}

extern "C" void kernel_launch(void* const* d_in, const int* in_sizes, int n_in,
                              void* d_out, int out_size, void* d_ws, size_t ws_size,
                              hipStream_t stream) {
  const float* feature   = (const float*)d_in[0];
  const float* embedding = (const float*)d_in[1];
  const float* weight    = (const float*)d_in[2];
  float* out = (float*)d_out;

  float* ws  = (float*)d_ws;
  float* nn  = ws;                                   // B*T f32
  float* dl  = nn + (size_t)B_ * T_;                 // B*T f32
  float* sim = dl + (size_t)B_ * T_;                 // B*3*T f32
  ushort_t* wbf = (ushort_t*)(sim + (size_t)3 * B_ * T_);   // O*KP bf16
  ushort_t* Ftp = wbf + (size_t)O_ * KP_;                   // B*FTP_ROWS*C bf16 (~33.6MB)

  zero_pads_kernel<<<dim3(B_, 3), 64, 0, stream>>>(Ftp);
  sim_reduce_kernel<<<dim3(T_ / 256, B_), dim3(64, 4), 0, stream>>>(embedding, nn, dl);
  sim_finalize_kernel<<<dim3((B_ * T_) / 256), 256, 0, stream>>>(nn, dl, sim);
  wperm_kernel<<<dim3((O_ * KP_ + 255) / 256), 256, 0, stream>>>(weight, wbf);
  transpose_kernel<<<dim3(T_ / 64, C_ / 64, B_), 256, 0, stream>>>(feature, Ftp);
  conv_gemm_kernel<<<dim3(T_ / TILE, O_ / TILE, B_), 256, 0, stream>>>(Ftp, wbf, sim, out);
}

// Round 3
// 117.951 us; speedup vs baseline: 1.9617x; 1.1614x over previous
//
#include <hip/hip_runtime.h>
#include <hip/hip_bf16.h>
#include <stdint.h>

#define B_ 8
#define C_ 512
#define T_ 4096
#define O_ 512
#define KP_ 1728   /* padded K: 3 groups x 3 k x 192 */
#define EPS_ 1e-8f

#define BM 256
#define BN 128
#define FTP_ROWS 4104  /* rows 0..4097 used (t=-1..T+1), stride padded */

#define LDS_A_USH 16384   /* 256x64 bf16 */
#define LDS_B_USH 8192    /* 128x64 bf16 */
#define LDS_BUF_USH 24576
#define LDS_BYTES (3 * LDS_BUF_USH * 2)  /* 147456 */

typedef unsigned short ushort_t;
typedef __attribute__((ext_vector_type(4))) float f32x4;
typedef __attribute__((ext_vector_type(8))) short bf16x8;

__device__ __forceinline__ ushort_t f2bf(float f) {
  union { float f; uint32_t u; } x; x.f = f;
  uint32_t u = x.u;
  uint32_t r = (u + 0x7FFFu + ((u >> 16) & 1u)) >> 16;
  return (ushort_t)r;
}

#define GLOAD16(gsrc, ldst) \
  __builtin_amdgcn_global_load_lds((const __attribute__((address_space(1))) unsigned int*)(gsrc), \
                                   (__attribute__((address_space(3))) unsigned int*)(ldst), 16, 0, 0)

// ---------------- sim reduction: nn[t] = sum_c e^2, dl[t] = sum_c e[t]*e[t-1] ---------
__global__ void sim_reduce_kernel(const float* __restrict__ emb,
                                  float* __restrict__ nn_out,
                                  float* __restrict__ dl_out) {
  const int b = blockIdx.y;
  const int t0 = (blockIdx.x * 64 + threadIdx.x) * 4;
  const int cty = threadIdx.y;
  float nn0=0.f,nn1=0.f,nn2=0.f,nn3=0.f;
  float dl0=0.f,dl1=0.f,dl2=0.f,dl3=0.f;
  const float* base = emb + (size_t)b * C_ * T_;
  for (int c = cty * 128; c < cty * 128 + 128; ++c) {
    const float* row = base + (size_t)c * T_;
    float4 v = *(const float4*)(row + t0);
    float el = (t0 > 0) ? row[t0 - 1] : 0.f;
    nn0 += v.x*v.x; nn1 += v.y*v.y; nn2 += v.z*v.z; nn3 += v.w*v.w;
    dl0 += v.x*el;  dl1 += v.y*v.x; dl2 += v.z*v.y; dl3 += v.w*v.z;
  }
  __shared__ float red[4][64*8];
  float* myr = &red[cty][threadIdx.x * 8];
  if (cty != 0) {
    myr[0]=nn0; myr[1]=nn1; myr[2]=nn2; myr[3]=nn3;
    myr[4]=dl0; myr[5]=dl1; myr[6]=dl2; myr[7]=dl3;
  }
  __syncthreads();
  if (cty == 0) {
    for (int q = 1; q < 4; ++q) {
      float* r = &red[q][threadIdx.x * 8];
      nn0+=r[0]; nn1+=r[1]; nn2+=r[2]; nn3+=r[3];
      dl0+=r[4]; dl1+=r[5]; dl2+=r[6]; dl3+=r[7];
    }
    float* nb = nn_out + (size_t)b * T_ + t0;
    float* db = dl_out + (size_t)b * T_ + t0;
    nb[0]=nn0; nb[1]=nn1; nb[2]=nn2; nb[3]=nn3;
    db[0]=dl0; db[1]=dl1; db[2]=dl2; db[3]=dl3;
  }
}

// ---------------- sim finalize ----------------
__global__ void sim_finalize_kernel(const float* __restrict__ nn,
                                    const float* __restrict__ dl,
                                    float* __restrict__ sim) {
  const int idx = blockIdx.x * 256 + threadIdx.x;
  if (idx >= B_ * T_) return;
  const int b = idx >> 12;
  const int t = idx & (T_ - 1);
  const float* nnb = nn + (size_t)b * T_;
  const float* dlb = dl + (size_t)b * T_;
  float nncur = nnb[t];
  float ncur = fmaxf(sqrtf(nncur), EPS_);
  float sc = nncur / (ncur * ncur);
  float sl = 0.f, sr = 0.f;
  if (t > 0) {
    float np = fmaxf(sqrtf(nnb[t - 1]), EPS_);
    sl = dlb[t] / (ncur * np);
  }
  if (t < T_ - 1) {
    float nx = fmaxf(sqrtf(nnb[t + 1]), EPS_);
    sr = dlb[t + 1] / (ncur * nx);
  }
  float* simb = sim + (size_t)b * 3 * T_;
  simb[t] = sl;
  simb[T_ + t] = sc;
  simb[2 * T_ + t] = sr;
}

// ---------------- weight permute+pad: wbf[o][p], p=(g*3+k)*192+j, c=(c_lo&~7)+j ------
__global__ void wperm_kernel(const float* __restrict__ w, ushort_t* __restrict__ wbf) {
  const int idx = blockIdx.x * 256 + threadIdx.x;
  if (idx >= O_ * KP_) return;
  const int o = idx / KP_;
  const int p = idx - o * KP_;
  const int g = p / 576; const int r = p - g * 576;
  const int k = r / 192; const int j = r - k * 192;
  const int c_lo = (512 * g - k + 2) / 3;
  const int c_hi = (512 * g + 511 - k) / 3;
  const int c = (c_lo & ~7) + j;
  float v = (c >= c_lo && c <= c_hi) ? w[((size_t)o * C_ + c) * 3 + k] : 0.f;
  wbf[idx] = f2bf(v);
}

// ---------------- zero pad rows of Ftp (t=-1, t=T, overrun row) ----------------------
__global__ void zero_pads_kernel(ushort_t* __restrict__ Ftp) {
  const int b = blockIdx.x;
  const int rsel = blockIdx.y;
  const int row = (rsel == 0) ? 0 : (rsel == 1 ? T_ + 1 : T_ + 2);
  uint4* dst = (uint4*)(Ftp + ((size_t)b * FTP_ROWS + row) * 512);
  if (threadIdx.x < 64) dst[threadIdx.x] = make_uint4(0, 0, 0, 0);
}

// ---------------- feature transpose+convert: Ftp[b][t+1][c] = bf16(feat[b][c][t]) ----
__global__ void transpose_kernel(const float* __restrict__ feat, ushort_t* __restrict__ Ftp) {
  const int b = blockIdx.z;
  const int c0 = blockIdx.y * 64;
  const int t0 = blockIdx.x * 64;
  __shared__ ushort_t LT[64 * 72];
  const int tid = threadIdx.x;
  {
    const int cl = tid >> 2;
    const int tq = (tid & 3) * 16;
    const float* src = feat + ((size_t)b * C_ + c0 + cl) * T_ + t0 + tq;
    for (int q = 0; q < 4; ++q) {
      float4 v = *(const float4*)(src + q * 4);
      const int t = tq + q * 4;
      LT[(t + 0) * 72 + cl] = f2bf(v.x);
      LT[(t + 1) * 72 + cl] = f2bf(v.y);
      LT[(t + 2) * 72 + cl] = f2bf(v.z);
      LT[(t + 3) * 72 + cl] = f2bf(v.w);
    }
  }
  __syncthreads();
  {
    const int tl = tid >> 2;
    const int cq = (tid & 3) * 16;
    ushort_t* dst = Ftp + ((size_t)b * FTP_ROWS + t0 + tl + 1) * 512 + c0 + cq;
    *(uint4*)(dst) = *(const uint4*)&LT[tl * 72 + cq];
    *(uint4*)(dst + 8) = *(const uint4*)&LT[tl * 72 + cq + 8];
  }
}

// ---------------- main GEMM: 256x128 tile, BK=64, triple-buffer, counted vmcnt -------
__global__ __launch_bounds__(512, 2)
void conv_gemm_kernel(const ushort_t* __restrict__ Ftp,
                      const ushort_t* __restrict__ wbf,
                      const float* __restrict__ sim,
                      float* __restrict__ out) {
  extern __shared__ ushort_t lds[];

  const int b = blockIdx.z;
  const int oBase = blockIdx.y * BM;
  const int tBase = blockIdx.x * BN;

  const int tid = threadIdx.x;
  const int lane = tid & 63;
  const int wid = tid >> 6;           // 8 waves
  const int wm = wid >> 1;            // 0..3 (o)
  const int wn = wid & 1;             // 0..1 (t)
  const int llo = lane & 15, lhi = lane >> 4;

  // staging geometry: row-in-64-stripe + inverse-swizzled source chunk
  const int rbase = wid * 8 + (lane >> 3);                 // 0..63
  const int sw = (((lane & 7) ^ ((lane >> 3) & 7)) << 3);  // ushort offset

  const ushort_t* ftpB = Ftp + (size_t)b * FTP_ROWS * 512;
  const float* simB = sim + (size_t)b * 3 * T_;

  // ---- preload sim (pin so loads complete before prologue; keeps vmcnt counts exact)
  float sv[3][4];
#pragma unroll
  for (int g = 0; g < 3; ++g)
#pragma unroll
    for (int n = 0; n < 4; ++n) {
      sv[g][n] = simB[g * T_ + tBase + wn * 64 + n * 16 + llo];
      asm volatile("" : "+v"(sv[g][n]));
    }

  f32x4 cacc[4][4], oacc[4][4];
  const f32x4 vzero = {0.f, 0.f, 0.f, 0.f};
#pragma unroll
  for (int m = 0; m < 4; ++m)
#pragma unroll
    for (int n = 0; n < 4; ++n) { cacc[m][n] = vzero; oacc[m][n] = vzero; }

  // ---- stage slab s2 into buffer p (6 global_load_lds: 4 A + 2 B) ----
  auto STAGE = [&](int s2, int p) {
    const int g = s2 / 9, r = s2 - g * 9, k = r / 3, jb = r - k * 3;
    const int c_lo = (512 * g - k + 2) / 3;
    const int c_st = c_lo & ~7;
    const ushort_t* aS = wbf + (size_t)(oBase + rbase) * KP_ + s2 * 64 + sw;
    const ushort_t* bS = ftpB + (size_t)(tBase + rbase + k) * 512 + c_st + jb * 64 + sw;
    ushort_t* Ad = lds + p * LDS_BUF_USH + wid * 512;
    ushort_t* Bd = lds + p * LDS_BUF_USH + LDS_A_USH + wid * 512;
#pragma unroll
    for (int i = 0; i < 4; ++i)
      GLOAD16(aS + (size_t)i * 64 * KP_, Ad + i * 4096);
#pragma unroll
    for (int i = 0; i < 2; ++i)
      GLOAD16(bS + (size_t)i * 64 * 512, Bd + i * 4096);
  };

  // ---- prologue: 3-deep prefetch (18 loads in flight) ----
  STAGE(0, 0); STAGE(1, 1); STAGE(2, 2);

#pragma unroll
  for (int s = 0; s < 27; ++s) {
    // wait own slab-s loads (12 = 2 newer slabs x 6 loads still allowed in flight)
    if (s <= 24)      { asm volatile("s_waitcnt vmcnt(12)" ::: "memory"); }
    else if (s == 25) { asm volatile("s_waitcnt vmcnt(6)" ::: "memory"); }
    else              { asm volatile("s_waitcnt vmcnt(0)" ::: "memory"); }
    __builtin_amdgcn_s_barrier();          // all waves' slab-s loads landed
    asm volatile("" ::: "memory");

    const int p = s % 3;
    const ushort_t* As = lds + p * LDS_BUF_USH;
    const ushort_t* Bs = As + LDS_A_USH;
#pragma unroll
    for (int h = 0; h < 2; ++h) {
      bf16x8 af[4], bfv[4];
#pragma unroll
      for (int m = 0; m < 4; ++m) {
        const int row = wm * 64 + m * 16 + llo;
        af[m] = *(const bf16x8*)&As[row * 64 + (((h * 4 + lhi) ^ (llo & 7)) << 3)];
      }
#pragma unroll
      for (int n = 0; n < 4; ++n) {
        const int row = wn * 64 + n * 16 + llo;
        bfv[n] = *(const bf16x8*)&Bs[row * 64 + (((h * 4 + lhi) ^ (llo & 7)) << 3)];
      }
      __builtin_amdgcn_s_setprio(1);
#pragma unroll
      for (int m = 0; m < 4; ++m)
#pragma unroll
        for (int n = 0; n < 4; ++n)
          cacc[m][n] = __builtin_amdgcn_mfma_f32_16x16x32_bf16(af[m], bfv[n], cacc[m][n], 0, 0, 0);
      __builtin_amdgcn_s_setprio(0);
    }

    __builtin_amdgcn_sched_barrier(0);
    asm volatile("" ::: "memory");
    __builtin_amdgcn_s_barrier();          // all waves done reading buffer p
    asm volatile("" ::: "memory");

    if (s + 3 < 27) STAGE(s + 3, p);       // overwrite buffer p with slab s+3

    // group boundary: fold sim_g * partial into output accumulator
    if (s == 8 || s == 17 || s == 26) {
      const int g = s / 9;
#pragma unroll
      for (int n = 0; n < 4; ++n) {
        const float sc = sv[g][n];
#pragma unroll
        for (int m = 0; m < 4; ++m) {
          oacc[m][n] += sc * cacc[m][n];
          cacc[m][n] = vzero;
        }
      }
    }
  }

  // ---- epilogue: D layout col=lane&15, row=(lane>>4)*4+reg ----
  float* outB = out + ((size_t)b * O_ + oBase) * T_ + tBase;
#pragma unroll
  for (int m = 0; m < 4; ++m) {
    const int r0 = wm * 64 + m * 16 + lhi * 4;
#pragma unroll
    for (int n = 0; n < 4; ++n) {
      const int cg = wn * 64 + n * 16 + llo;
#pragma unroll
      for (int r = 0; r < 4; ++r)
        outB[(size_t)(r0 + r) * T_ + cg] = oacc[m][n][r];
    }
  }
}

extern "C" void kernel_launch(void* const* d_in, const int* in_sizes, int n_in,
                              void* d_out, int out_size, void* d_ws, size_t ws_size,
                              hipStream_t stream) {
  const float* feature   = (const float*)d_in[0];
  const float* embedding = (const float*)d_in[1];
  const float* weight    = (const float*)d_in[2];
  float* out = (float*)d_out;

  float* ws  = (float*)d_ws;
  float* nn  = ws;                                   // B*T f32
  float* dl  = nn + (size_t)B_ * T_;                 // B*T f32
  float* sim = dl + (size_t)B_ * T_;                 // B*3*T f32
  ushort_t* wbf = (ushort_t*)(sim + (size_t)3 * B_ * T_);   // O*KP bf16
  ushort_t* Ftp = wbf + (size_t)O_ * KP_;                   // B*FTP_ROWS*C bf16

  (void)hipFuncSetAttribute((const void*)conv_gemm_kernel,
                            hipFuncAttributeMaxDynamicSharedMemorySize, LDS_BYTES);

  zero_pads_kernel<<<dim3(B_, 3), 64, 0, stream>>>(Ftp);
  sim_reduce_kernel<<<dim3(T_ / 256, B_), dim3(64, 4), 0, stream>>>(embedding, nn, dl);
  sim_finalize_kernel<<<dim3((B_ * T_) / 256), 256, 0, stream>>>(nn, dl, sim);
  wperm_kernel<<<dim3((O_ * KP_ + 255) / 256), 256, 0, stream>>>(weight, wbf);
  transpose_kernel<<<dim3(T_ / 64, C_ / 64, B_), 256, 0, stream>>>(feature, Ftp);
  conv_gemm_kernel<<<dim3(T_ / BN, O_ / BM, B_), 512, LDS_BYTES, stream>>>(Ftp, wbf, sim, out);
}

// Round 5
// 115.412 us; speedup vs baseline: 2.0049x; 1.0220x over previous
//
#include <hip/hip_runtime.h>
#include <hip/hip_bf16.h>
#include <stdint.h>

#define B_ 8
#define C_ 512
#define T_ 4096
#define O_ 512
#define KP_ 1728   /* padded K: 3 groups x 3 k x 192 */
#define EPS_ 1e-8f

#define BM 256
#define BN 128
#define FTP_ROWS 4104

/* LDS ring: 4 half-slab buffers, each [A 256x32 = 8192 ush][B 128x32 = 4096 ush] */
#define RING_USH 12288
#define LDS_BYTES (4 * RING_USH * 2)  /* 98304 */

typedef unsigned short ushort_t;
typedef __attribute__((ext_vector_type(4))) float f32x4;
typedef __attribute__((ext_vector_type(8))) short bf16x8;

__device__ __forceinline__ ushort_t f2bf(float f) {
  union { float f; uint32_t u; } x; x.f = f;
  uint32_t u = x.u;
  uint32_t r = (u + 0x7FFFu + ((u >> 16) & 1u)) >> 16;
  return (ushort_t)r;
}

#define GLOAD16(gsrc, ldst) \
  __builtin_amdgcn_global_load_lds((const __attribute__((address_space(1))) unsigned int*)(gsrc), \
                                   (__attribute__((address_space(3))) unsigned int*)(ldst), 16, 0, 0)

// ---------------- sim reduction: nn[t] = sum_c e^2, dl[t] = sum_c e[t]*e[t-1] ---------
__global__ void sim_reduce_kernel(const float* __restrict__ emb,
                                  float* __restrict__ nn_out,
                                  float* __restrict__ dl_out) {
  const int b = blockIdx.y;
  const int t0 = (blockIdx.x * 64 + threadIdx.x) * 4;
  const int cty = threadIdx.y;
  float nn0=0.f,nn1=0.f,nn2=0.f,nn3=0.f;
  float dl0=0.f,dl1=0.f,dl2=0.f,dl3=0.f;
  const float* base = emb + (size_t)b * C_ * T_;
  for (int c = cty * 128; c < cty * 128 + 128; ++c) {
    const float* row = base + (size_t)c * T_;
    float4 v = *(const float4*)(row + t0);
    float el = (t0 > 0) ? row[t0 - 1] : 0.f;
    nn0 += v.x*v.x; nn1 += v.y*v.y; nn2 += v.z*v.z; nn3 += v.w*v.w;
    dl0 += v.x*el;  dl1 += v.y*v.x; dl2 += v.z*v.y; dl3 += v.w*v.z;
  }
  __shared__ float red[4][64*8];
  float* myr = &red[cty][threadIdx.x * 8];
  if (cty != 0) {
    myr[0]=nn0; myr[1]=nn1; myr[2]=nn2; myr[3]=nn3;
    myr[4]=dl0; myr[5]=dl1; myr[6]=dl2; myr[7]=dl3;
  }
  __syncthreads();
  if (cty == 0) {
    for (int q = 1; q < 4; ++q) {
      float* r = &red[q][threadIdx.x * 8];
      nn0+=r[0]; nn1+=r[1]; nn2+=r[2]; nn3+=r[3];
      dl0+=r[4]; dl1+=r[5]; dl2+=r[6]; dl3+=r[7];
    }
    float* nb = nn_out + (size_t)b * T_ + t0;
    float* db = dl_out + (size_t)b * T_ + t0;
    nb[0]=nn0; nb[1]=nn1; nb[2]=nn2; nb[3]=nn3;
    db[0]=dl0; db[1]=dl1; db[2]=dl2; db[3]=dl3;
  }
}

// ---------------- fused: sim finalize (blocks 0..127) + weight permute (rest) --------
__global__ void prep_small_kernel(const float* __restrict__ nn,
                                  const float* __restrict__ dl,
                                  float* __restrict__ sim,
                                  const float* __restrict__ w,
                                  ushort_t* __restrict__ wbf) {
  const int bid = blockIdx.x;
  if (bid < 128) {
    const int idx = bid * 256 + threadIdx.x;
    const int b = idx >> 12;
    const int t = idx & (T_ - 1);
    const float* nnb = nn + (size_t)b * T_;
    const float* dlb = dl + (size_t)b * T_;
    float nncur = nnb[t];
    float ncur = fmaxf(sqrtf(nncur), EPS_);
    float sc = nncur / (ncur * ncur);
    float sl = 0.f, sr = 0.f;
    if (t > 0) {
      float np = fmaxf(sqrtf(nnb[t - 1]), EPS_);
      sl = dlb[t] / (ncur * np);
    }
    if (t < T_ - 1) {
      float nx = fmaxf(sqrtf(nnb[t + 1]), EPS_);
      sr = dlb[t + 1] / (ncur * nx);
    }
    float* simb = sim + (size_t)b * 3 * T_;
    simb[t] = sl;
    simb[T_ + t] = sc;
    simb[2 * T_ + t] = sr;
  } else {
    const int idx = (bid - 128) * 256 + threadIdx.x;
    if (idx >= O_ * KP_) return;
    const int o = idx / KP_;
    const int p = idx - o * KP_;
    const int g = p / 576; const int r = p - g * 576;
    const int k = r / 192; const int j = r - k * 192;
    const int c_lo = (512 * g - k + 2) / 3;
    const int c_hi = (512 * g + 511 - k) / 3;
    const int c = (c_lo & ~7) + j;
    float v = (c >= c_lo && c <= c_hi) ? w[((size_t)o * C_ + c) * 3 + k] : 0.f;
    wbf[idx] = f2bf(v);
  }
}

// ---------------- feature transpose+convert (+ zero pad rows when x==64) -------------
__global__ void transpose_kernel(const float* __restrict__ feat, ushort_t* __restrict__ Ftp) {
  const int b = blockIdx.z;
  const int c0 = blockIdx.y * 64;
  const int tid = threadIdx.x;
  if (blockIdx.x == T_ / 64) {  // pad rows t=-1 (row 0) and t=T (row 4097)
    if (tid < 64)        Ftp[((size_t)b * FTP_ROWS + 0) * 512 + c0 + tid] = 0;
    else if (tid < 128)  Ftp[((size_t)b * FTP_ROWS + T_ + 1) * 512 + c0 + (tid - 64)] = 0;
    return;
  }
  const int t0 = blockIdx.x * 64;
  __shared__ ushort_t LT[64 * 72];
  {
    const int cl = tid >> 2;
    const int tq = (tid & 3) * 16;
    const float* src = feat + ((size_t)b * C_ + c0 + cl) * T_ + t0 + tq;
    for (int q = 0; q < 4; ++q) {
      float4 v = *(const float4*)(src + q * 4);
      const int t = tq + q * 4;
      LT[(t + 0) * 72 + cl] = f2bf(v.x);
      LT[(t + 1) * 72 + cl] = f2bf(v.y);
      LT[(t + 2) * 72 + cl] = f2bf(v.z);
      LT[(t + 3) * 72 + cl] = f2bf(v.w);
    }
  }
  __syncthreads();
  {
    const int tl = tid >> 2;
    const int cq = (tid & 3) * 16;
    ushort_t* dst = Ftp + ((size_t)b * FTP_ROWS + t0 + tl + 1) * 512 + c0 + cq;
    *(uint4*)(dst) = *(const uint4*)&LT[tl * 72 + cq];
    *(uint4*)(dst + 8) = *(const uint4*)&LT[tl * 72 + cq + 8];
  }
}

// ---------------- main GEMM: 256x128, 4-deep half-slab ring, counted vmcnt -----------
__global__ __launch_bounds__(512, 2)
void conv_gemm_kernel(const ushort_t* __restrict__ Ftp,
                      const ushort_t* __restrict__ wbf,
                      const float* __restrict__ sim,
                      float* __restrict__ out) {
  extern __shared__ ushort_t lds[];

  const int b = blockIdx.z;
  const int oBase = blockIdx.y * BM;
  const int tBase = blockIdx.x * BN;

  const int tid = threadIdx.x;
  const int lane = tid & 63;
  const int wid = tid >> 6;           // 8 waves
  const int wm = wid >> 1;            // 0..3 (o)
  const int wn = wid & 1;             // 0..1 (t)
  const int llo = lane & 15, lhi = lane >> 4;

  // ds_read chunk swizzle (2-way banks = free; 8-lane groups bank-distinct)
  const int rdsw = ((lhi ^ ((llo >> 1) & 3)) << 3);
  // staging: row-in-stripe = lane>>2, source chunk = (lane&3) ^ ((lane>>3)&3)
  const int gch = ((lane & 3) ^ ((lane >> 3) & 3)) << 3;
  const int arow = wid * 32 + (lane >> 2);   // A rows (second instr adds 16)
  const int brow = wid * 16 + (lane >> 2);   // B rows

  const ushort_t* ftpB = Ftp + (size_t)b * FTP_ROWS * 512;
  const float* simB = sim + (size_t)b * 3 * T_;

  // ---- preload sim, then drain so vmcnt counting stays exact ----
  float sv[3][4];
#pragma unroll
  for (int g = 0; g < 3; ++g)
#pragma unroll
    for (int n = 0; n < 4; ++n) {
      sv[g][n] = simB[g * T_ + tBase + wn * 64 + n * 16 + llo];
      asm volatile("" : "+v"(sv[g][n]));
    }
  asm volatile("s_waitcnt vmcnt(0)" ::: "memory");

  f32x4 cacc[4][4], oacc[4][4];
  const f32x4 vzero = {0.f, 0.f, 0.f, 0.f};
#pragma unroll
  for (int m = 0; m < 4; ++m)
#pragma unroll
    for (int n = 0; n < 4; ++n) { cacc[m][n] = vzero; oacc[m][n] = vzero; }

  // ---- stage half-slab u into ring[u&3]: 2 A-loads + 1 B-load per thread ----
  auto STAGE = [&](int u) {
    const int s2 = u >> 1, h = u & 1;
    const int g = s2 / 9, r = s2 - g * 9, k = r / 3, jb = r - k * 3;
    const int c_st = ((512 * g - k + 2) / 3) & ~7;
    ushort_t* ring = lds + (u & 3) * RING_USH;
    const ushort_t* aS = wbf + (size_t)(oBase + arow) * KP_ + s2 * 64 + h * 32 + gch;
    GLOAD16(aS, ring + wid * 1024);
    GLOAD16(aS + (size_t)16 * KP_, ring + wid * 1024 + 512);
    const ushort_t* bS = ftpB + (size_t)(tBase + brow + k) * 512 + c_st + jb * 64 + h * 32 + gch;
    GLOAD16(bS, ring + 8192 + wid * 512);
  };

  // ---- one phase: wait -> barrier -> read -> stage u+3 -> MFMA -> lgkm drain ----
  auto PHASE = [&](int u, int vm) {
    if (vm == 6)      { asm volatile("s_waitcnt vmcnt(6)" ::: "memory"); }
    else if (vm == 3) { asm volatile("s_waitcnt vmcnt(3)" ::: "memory"); }
    else              { asm volatile("s_waitcnt vmcnt(0)" ::: "memory"); }
    __builtin_amdgcn_s_barrier();      // all waves: half-slab u landed; prev readers drained
    asm volatile("" ::: "memory");

    const ushort_t* Ah = lds + (u & 3) * RING_USH;
    const ushort_t* Bh = Ah + 8192;
    bf16x8 af[4], bfv[4];
#pragma unroll
    for (int m = 0; m < 4; ++m)
      af[m] = *(const bf16x8*)&Ah[(wm * 64 + m * 16 + llo) * 32 + rdsw];
#pragma unroll
    for (int n = 0; n < 4; ++n)
      bfv[n] = *(const bf16x8*)&Bh[(wn * 64 + n * 16 + llo) * 32 + rdsw];

    if (u + 3 < 54) STAGE(u + 3);

    __builtin_amdgcn_s_setprio(1);
#pragma unroll
    for (int m = 0; m < 4; ++m)
#pragma unroll
      for (int n = 0; n < 4; ++n)
        cacc[m][n] = __builtin_amdgcn_mfma_f32_16x16x32_bf16(af[m], bfv[n], cacc[m][n], 0, 0, 0);
    __builtin_amdgcn_s_setprio(0);

    asm volatile("s_waitcnt lgkmcnt(0)" ::: "memory");  // my reads retired before next barrier
    __builtin_amdgcn_sched_barrier(0);
  };

  // ---- prologue: 3 half-slabs in flight (9 loads) ----
  STAGE(0); STAGE(1); STAGE(2);

#pragma unroll
  for (int s = 0; s < 27; ++s) {
    const int u0 = 2 * s, u1 = 2 * s + 1;
    PHASE(u0, u0 < 52 ? 6 : 3);
    PHASE(u1, u1 < 52 ? 6 : 0);
    if (s == 8 || s == 17 || s == 26) {
      const int g = s / 9;
#pragma unroll
      for (int n = 0; n < 4; ++n) {
        const float sc = sv[g][n];
#pragma unroll
        for (int m = 0; m < 4; ++m) {
          oacc[m][n] += sc * cacc[m][n];
          cacc[m][n] = vzero;
        }
      }
    }
  }

  // ---- epilogue: D layout col=lane&15, row=(lane>>4)*4+reg ----
  float* outB = out + ((size_t)b * O_ + oBase) * T_ + tBase;
#pragma unroll
  for (int m = 0; m < 4; ++m) {
    const int r0 = wm * 64 + m * 16 + lhi * 4;
#pragma unroll
    for (int n = 0; n < 4; ++n) {
      const int cg = wn * 64 + n * 16 + llo;
#pragma unroll
      for (int r = 0; r < 4; ++r)
        outB[(size_t)(r0 + r) * T_ + cg] = oacc[m][n][r];
    }
  }
}

extern "C" void kernel_launch(void* const* d_in, const int* in_sizes, int n_in,
                              void* d_out, int out_size, void* d_ws, size_t ws_size,
                              hipStream_t stream) {
  const float* feature   = (const float*)d_in[0];
  const float* embedding = (const float*)d_in[1];
  const float* weight    = (const float*)d_in[2];
  float* out = (float*)d_out;

  float* ws  = (float*)d_ws;
  float* nn  = ws;                                   // B*T f32
  float* dl  = nn + (size_t)B_ * T_;                 // B*T f32
  float* sim = dl + (size_t)B_ * T_;                 // B*3*T f32
  ushort_t* wbf = (ushort_t*)(sim + (size_t)3 * B_ * T_);   // O*KP bf16
  ushort_t* Ftp = wbf + (size_t)O_ * KP_;                   // B*FTP_ROWS*C bf16

  (void)hipFuncSetAttribute((const void*)conv_gemm_kernel,
                            hipFuncAttributeMaxDynamicSharedMemorySize, LDS_BYTES);

  sim_reduce_kernel<<<dim3(T_ / 256, B_), dim3(64, 4), 0, stream>>>(embedding, nn, dl);
  prep_small_kernel<<<dim3(128 + (O_ * KP_ + 255) / 256), 256, 0, stream>>>(nn, dl, sim, weight, wbf);
  transpose_kernel<<<dim3(T_ / 64 + 1, C_ / 64, B_), 256, 0, stream>>>(feature, Ftp);
  conv_gemm_kernel<<<dim3(T_ / BN, O_ / BM, B_), 512, LDS_BYTES, stream>>>(Ftp, wbf, sim, out);
}